// Round 1
// 128.442 us; speedup vs baseline: 1.0694x; 1.0694x over previous
//
#include <hip/hip_runtime.h>
#include <hip/hip_bf16.h>
#include <math.h>

// Problem constants
#define T_STEPS 100
#define H_DIM   50
#define Z_DIM   10
#define OUT_DIM 65   // Z + Z*(Z+1)/2 = 10 + 55
#define KP      25   // f16 pairs per gate column

typedef _Float16 half2v __attribute__((ext_vector_type(2)));

// ---- cross-lane primitives ----
__device__ __forceinline__ float bcast_lane(float v, int lane) {
    return __uint_as_float(__builtin_amdgcn_readlane(__float_as_uint(v), lane));
}
__device__ __forceinline__ unsigned readlane_u(unsigned v, int lane) {
    return (unsigned)__builtin_amdgcn_readlane((int)v, lane);
}
// DPP cross-lane fetch (VALU speed). bound_ctrl=1 -> invalid source reads 0.
template<int CTRL>
__device__ __forceinline__ float dpp_mov(float x) {
    return __uint_as_float((unsigned)__builtin_amdgcn_update_dpp(
        0, (int)__float_as_uint(x), CTRL, 0xF, 0xF, true));
}
#define DPP_ROW_SHL1 0x101   // lane i <- lane i+1
#define DPP_SHR1     0x111
#define DPP_SHR2     0x112
#define DPP_SHR4     0x114
#define DPP_SHR8     0x118
#define DPP_BCAST15  0x142
#define DPP_BCAST31  0x143

// ---- packed f16 helpers ----
__device__ __forceinline__ unsigned pack_h2(float lo, float hi) {
#if __has_builtin(__builtin_amdgcn_cvt_pkrtz)
    return __builtin_bit_cast(unsigned, __builtin_amdgcn_cvt_pkrtz(lo, hi));
#else
    half2v p; p.x = (_Float16)lo; p.y = (_Float16)hi;
    return __builtin_bit_cast(unsigned, p);
#endif
}
__device__ __forceinline__ float fdot2h(unsigned a, unsigned b, float c) {
#if __has_builtin(__builtin_amdgcn_fdot2)
    return __builtin_amdgcn_fdot2(__builtin_bit_cast(half2v, a),
                                  __builtin_bit_cast(half2v, b), c, false);
#else
    const half2v x = __builtin_bit_cast(half2v, a);
    const half2v y = __builtin_bit_cast(half2v, b);
    return fmaf((float)x.x, (float)y.x, fmaf((float)x.y, (float)y.y, c));
#endif
}

// ---- fast math ----
__device__ __forceinline__ float fast_rcp(float x) { return __builtin_amdgcn_rcpf(x); }
__device__ __forceinline__ float fast_rsq(float x) { return __builtin_amdgcn_rsqf(x); }
__device__ __forceinline__ float fast_sigmoid(float x) {
    return fast_rcp(1.0f + __expf(-x));
}
__device__ __forceinline__ float fast_tanh(float y) {
    return 1.0f - 2.0f * fast_rcp(__expf(2.0f * y) + 1.0f);
}

// =====================================================================
// Kernel 1: serial recurrence, 3 waves (one gate per wave).
// Per step: each wave does ITS gate's matvec (25 dot2) + LN tree over
// 2 quantities, writes the gate vector to a double-buffered LDS strip,
// ONE barrier, then all waves redundantly combine to the new h.
// h history is kept in LDS (no per-step global store -> barriers wait
// only on lgkmcnt) and dumped vectorized at the end.
// =====================================================================
__global__ __launch_bounds__(192, 1)
void gru_recur_kernel(
    const float* __restrict__ carry_init,
    const float* __restrict__ W_hr, const float* __restrict__ b_hr,
    const float* __restrict__ s_r,  const float* __restrict__ o_r,
    const float* __restrict__ W_hz, const float* __restrict__ b_hz,
    const float* __restrict__ s_z,  const float* __restrict__ o_z,
    const float* __restrict__ W_hn, const float* __restrict__ b_hn,
    const float* __restrict__ s_n,  const float* __restrict__ o_n,
    float* __restrict__ ws_h)
{
    const int  tid   = threadIdx.x;
    const int  wave  = tid >> 6;          // 0:r  1:z  2:n
    const int  j     = tid & 63;
    const bool valid = (j < H_DIM);
    const int  jc    = valid ? j : 0;

    // Per-wave gate parameter selection (wave-uniform branches).
    const float* Wg = (wave == 0) ? W_hr : (wave == 1) ? W_hz : W_hn;
    const float* bg = (wave == 0) ? b_hr : (wave == 1) ? b_hz : b_hn;
    const float* sg = (wave == 0) ? s_r  : (wave == 1) ? s_z  : s_n;
    const float* og = (wave == 0) ? o_r  : (wave == 1) ? o_z  : o_n;

    // Lane j: column j of this wave's gate W, packed f16 pairs over K.
    // Invalid lanes get zero weights/bias -> activations exactly 0 ->
    // LN stats need no masking.
    unsigned w[KP];
    #pragma unroll
    for (int k = 0; k < KP; ++k) {
        const int i0 = 2 * k, i1 = 2 * k + 1;
        w[k] = pack_h2(valid ? Wg[i0 * H_DIM + j] : 0.0f,
                       valid ? Wg[i1 * H_DIM + j] : 0.0f);
    }
    // Pin: forbid rematerializing the loads/converts inside the t-loop.
    #pragma unroll
    for (int k = 0; k < KP; ++k) asm volatile("" : "+v"(w[k]));

    const float bj = valid ? bg[jc] : 0.0f;
    const float sc = sg[jc];
    const float of = og[jc];

    __shared__ float gbuf[2][3][64];                    // double-buffered gate exchange
    __shared__ __align__(16) float hist[T_STEPS][64];   // h history, dumped at end

    float h = valid ? carry_init[jc] : 0.0f;
    const float invH = 1.0f / (float)H_DIM;

    // Packed broadcast source: even lane 2k holds (h_2k, h_{2k+1}).
    float    hsl = dpp_mov<DPP_ROW_SHL1>(h);
    unsigned hpk = pack_h2(h, hsl);

    #pragma unroll 1
    for (int t = 0; t < T_STEPS; ++t) {
        // ---- this wave's matvec via dot2: a_j = b_j + sum_i h_i*W[i][j] ----
        float a0 = bj, a1 = 0.0f;
        #pragma unroll
        for (int k = 0; k < KP; k += 2) {
            const unsigned s0 = readlane_u(hpk, 2 * k);
            a0 = fdot2h(s0, w[k], a0);
            if (k + 1 < KP) {
                const unsigned s1 = readlane_u(hpk, 2 * (k + 1));
                a1 = fdot2h(s1, w[k + 1], a1);
            }
        }
        const float a = a0 + a1;

        // ---- LN stats: 2 quantities, DPP tree ----
        float m = a, q = a * a;
        #define STAGE(C) m += dpp_mov<C>(m); q += dpp_mov<C>(q);
        STAGE(DPP_SHR1) STAGE(DPP_SHR2) STAGE(DPP_SHR4)
        STAGE(DPP_SHR8) STAGE(DPP_BCAST15) STAGE(DPP_BCAST31)
        #undef STAGE
        m = bcast_lane(m, 63); q = bcast_lane(q, 63);

        // ---- layernorm + this gate's activation ----
        const float mu  = m * invH;
        const float var = fmaxf(q * invH - mu * mu, 0.0f);
        const float g   = (a - mu) * fast_rsq(var + 1e-6f) * sc + of;
        const float val = (wave == 2) ? g : fast_sigmoid(g);   // n-gate: pre-tanh

        gbuf[t & 1][wave][j] = val;
        __syncthreads();   // one barrier/step; double buffer makes it sufficient

        // ---- combine (redundant in all 3 waves) ----
        const float r  = gbuf[t & 1][0][j];
        const float z  = gbuf[t & 1][1][j];
        const float gn = gbuf[t & 1][2][j];
        const float n  = fast_tanh(r * gn);
        h = n + z * (h - n);              // (1-z)*n + z*h

        if (wave == 0) hist[t][j] = h;

        // repack broadcast source for next step
        hsl = dpp_mov<DPP_ROW_SHL1>(h);
        hpk = pack_h2(h, hsl);
    }

    __syncthreads();
    // Vectorized LDS -> global dump of the whole history.
    {
        float4*       dst = (float4*)ws_h;
        const float4* src = (const float4*)hist;
        for (int i = tid; i < T_STEPS * 16; i += 192)
            dst[i] = src[i];
    }
}

// =====================================================================
// Kernel 2: dense projection + nat transform. One block per timestep.
// Forward substitution now column-parallel (10 register-resident chains)
// instead of a tid==0 serial LDS-latency chain.
// =====================================================================
__global__ __launch_bounds__(128)
void dense_nat_kernel(
    const float* __restrict__ W_dense, const float* __restrict__ b_dense,
    const float* __restrict__ ws_h, float* __restrict__ out)
{
    const int t   = blockIdx.x;
    const int tid = threadIdx.x;

    __shared__ float hloc[H_DIM];
    __shared__ float dl  [OUT_DIM];
    __shared__ float Lp  [55];
    __shared__ float Li  [55];
    __shared__ float Jsh [100];

    if (tid < H_DIM) hloc[tid] = ws_h[t * 64 + tid];
    __syncthreads();

    if (tid < OUT_DIM) {
        float acc = b_dense[tid];
        #pragma unroll
        for (int i = 0; i < H_DIM; ++i)
            acc = fmaf(hloc[i], W_dense[i * OUT_DIM + tid], acc);
        dl[tid] = acc;
    }
    __syncthreads();

    // Lp = packed lower-tri L with softplus applied to diagonal entries.
    if (tid < 55) {
        float v = dl[Z_DIM + tid];
        const bool isd = (tid==0)|(tid==2)|(tid==5)|(tid==9)|(tid==14)|
                         (tid==20)|(tid==27)|(tid==35)|(tid==44)|(tid==54);
        if (isd) v = (v > 20.0f) ? v : log1pf(__expf(v));
        Lp[tid] = v;
    }
    __syncthreads();

    float* outSigma = out;           // [100][10][10]
    float* outMu    = out + 10000;   // [100][10]
    float* outJ     = out + 11000;   // [100][10][10]
    float* outHnat  = out + 21000;   // [100][10]

    // Map flat tri index -> (a,b), a >= b
    int a = 0;
    {
        #pragma unroll
        for (int x = 1; x < Z_DIM; ++x)
            if (tid >= x * (x + 1) / 2) a = x;
    }
    const int b = tid - a * (a + 1) / 2;

    // Sigma = L @ L^T (one entry per thread)
    if (tid < 55) {
        float s = 0.0f;
        for (int k = 0; k <= b; ++k)
            s = fmaf(Lp[a * (a + 1) / 2 + k], Lp[b * (b + 1) / 2 + k], s);
        outSigma[t * 100 + a * 10 + b] = s;
        outSigma[t * 100 + b * 10 + a] = s;
    }
    if (tid >= 64 && tid < 64 + Z_DIM) outMu[t * 10 + (tid - 64)] = dl[tid - 64];
    __syncthreads();

    // Linv by forward substitution: thread k owns column k in registers.
    // col[m] = 0 for m < k makes the dot products exact with no predicate
    // (fmaf(x, 0, s) == s); nonzero-term order matches the serial version.
    if (tid < Z_DIM) {
        const int k = tid;
        float dinv[Z_DIM];
        #pragma unroll
        for (int i = 0; i < Z_DIM; ++i)
            dinv[i] = 1.0f / Lp[i * (i + 1) / 2 + i];
        float col[Z_DIM];
        #pragma unroll
        for (int i = 0; i < Z_DIM; ++i) col[i] = 0.0f;
        #pragma unroll
        for (int i = 0; i < Z_DIM; ++i) {
            float s = 0.0f;
            #pragma unroll
            for (int m = 0; m < i; ++m)
                s = fmaf(Lp[i * (i + 1) / 2 + m], col[m], s);
            if (i >= k) col[i] = (i == k) ? dinv[i] : -s * dinv[i];
        }
        #pragma unroll
        for (int i = 0; i < Z_DIM; ++i)
            if (i >= k) Li[i * (i + 1) / 2 + k] = col[i];
    }
    __syncthreads();

    // J = Linv^T @ Linv (one entry per thread)
    if (tid < 55) {
        float s = 0.0f;
        for (int m = a; m < Z_DIM; ++m)
            s = fmaf(Li[m * (m + 1) / 2 + a], Li[m * (m + 1) / 2 + b], s);
        outJ[t * 100 + a * 10 + b] = s;
        outJ[t * 100 + b * 10 + a] = s;
        Jsh[a * 10 + b] = s;
        Jsh[b * 10 + a] = s;
    }
    __syncthreads();

    // h_nat = J @ mu
    if (tid < Z_DIM) {
        float s = 0.0f;
        #pragma unroll
        for (int k = 0; k < Z_DIM; ++k)
            s = fmaf(Jsh[tid * 10 + k], dl[k], s);
        outHnat[t * 10 + tid] = s;
    }
}

extern "C" void kernel_launch(void* const* d_in, const int* in_sizes, int n_in,
                              void* d_out, int out_size, void* d_ws, size_t ws_size,
                              hipStream_t stream) {
    const float* p[15];
    for (int i = 0; i < 15; ++i) p[i] = (const float*)d_in[i];
    float* ws_h = (float*)d_ws;   // [T_STEPS][64] f32 = 25600 B

    gru_recur_kernel<<<dim3(1), dim3(192), 0, stream>>>(
        p[0],
        p[1], p[2], p[3], p[4],
        p[5], p[6], p[7], p[8],
        p[9], p[10], p[11], p[12],
        ws_h);

    dense_nat_kernel<<<dim3(T_STEPS), dim3(128), 0, stream>>>(
        p[13], p[14], ws_h, (float*)d_out);
}